// Round 3
// baseline (855.149 us; speedup 1.0000x reference)
//
#include <hip/hip_runtime.h>

#define BB 256
#define TT 512
#define NN 128
#define GO_IDX 1
#define EOS_IDX 2
#define TSPLIT 496            // bp rows t in [1,TSPLIT) in LDS; [TSPLIT,512) in d_ws
#define NEGV (-10000.0f)
#define AP 136                // padded alpha stride: half0 @ [0..63], half1 @ [68..131]

__global__ __launch_bounds__(256) void viterbi_kernel(
    const float* __restrict__ unaries,   // [B,T,N] RAW (log-softmax fused in)
    const float* __restrict__ trans,     // [1,N,N] trans0[cur][prev]
    const int*   __restrict__ lengths_raw,
    float* __restrict__ out,             // [B*T] preds then [B] scores
    unsigned char* __restrict__ ws)
{
    __shared__ unsigned char bps[(TSPLIT - 1) * NN];   // 63360 B
    __shared__ __align__(16) float alpha[2][AP];       // padded, double-buffered
    __shared__ float2 mls[16];                         // (m, ls) ring, 8-ahead
    __shared__ float fin_v[2];
    __shared__ int   fin_i[2];

    const int tid  = threadIdx.x;
    const int b    = blockIdx.x;
    const int wave = tid >> 6;
    const int lane = tid & 63;
    const int h    = lane & 1;             // prev-half owned by this lane
    const int cur  = wave * 32 + (lane >> 1);

    int len;
    {
        int probe = lengths_raw[1];        // ==0 iff int64 (lengths >= 256 > 0)
        len = (probe == 0) ? lengths_raw[2 * b] : lengths_raw[b];
    }

    // trans chunk in registers: trans0[cur][h*64 + j]
    float tr[64];
    {
        const float4* t4 = (const float4*)(trans + cur * NN + h * 64);
#pragma unroll
        for (int i = 0; i < 16; ++i) {
            float4 v = t4[i];
            tr[4*i+0] = v.x; tr[4*i+1] = v.y; tr[4*i+2] = v.z; tr[4*i+3] = v.w;
        }
    }

    // alpha init (store tag x at padded slot x + (x>>6)*4)
    if (tid < NN) alpha[0][tid + (tid >> 6) * 4] = (tid == GO_IDX) ? 0.0f : NEGV;

    const float* ub = unaries + (size_t)b * TT * NN;
    unsigned char* wst = ws + (size_t)b * ((TT - TSPLIT) * NN);

    // ---- prologue: (m,ls) for rows 0..7, each wave handles 2 rows ----
    {
        const int row = 2 * wave + (lane >> 5);
        const float4* r4 = (const float4*)(ub + row * NN);
        float4 u4 = r4[lane & 31];
        float m = fmaxf(fmaxf(u4.x, u4.y), fmaxf(u4.z, u4.w));
#pragma unroll
        for (int off = 16; off; off >>= 1) m = fmaxf(m, __shfl_xor(m, off, 64));
        float s = expf(u4.x - m) + expf(u4.y - m) + expf(u4.z - m) + expf(u4.w - m);
#pragma unroll
        for (int off = 16; off; off >>= 1) s += __shfl_xor(s, off, 64);
        if ((lane & 31) == 0) mls[row] = make_float2(m, logf(s));
    }

    // 8-deep register window of RAW u[t][cur] (even lanes)
    float P[8], Nx[8];
    if (h == 0) {
#pragma unroll
        for (int k = 0; k < 8; ++k) P[k] = ub[k * NN + cur];
    }
    // wave-3 ring of rows t+8 (float2 per lane)
    float2 VR[8];
    if (wave == 3) {
#pragma unroll
        for (int k = 0; k < 8; ++k) VR[k] = ((const float2*)(ub + (8 + k) * NN))[lane];
    }
    __syncthreads();

    const int nG = (len + 7) >> 3;
    for (int g = 0; g < nG; ++g) {
        const int tb = g * 8;
        if (h == 0) {
#pragma unroll
            for (int k = 0; k < 8; ++k) {
                int tt = tb + 8 + k; if (tt > TT - 1) tt = TT - 1;
                Nx[k] = ub[tt * NN + cur];
            }
        }
#pragma unroll
        for (int k = 0; k < 8; ++k) {
            const int t = tb + k;
            if (t < len) {                         // uniform per block
                const float*  ra = alpha[t & 1];
                float*        wa = alpha[(t & 1) ^ 1];
                const float4* a4 = (const float4*)(ra + h * 68);   // pad: halves 4 banks apart
                float bv[4]; int bi[4];
#pragma unroll
                for (int c = 0; c < 4; ++c) {
                    bv[c] = -INFINITY; bi[c] = 0;
#pragma unroll
                    for (int q = 0; q < 4; ++q) {
                        float4 a = a4[c * 4 + q];
                        const int base = c * 16 + q * 4;
                        float x0 = a.x + tr[base + 0]; if (x0 > bv[c]) { bv[c] = x0; bi[c] = base + 0; }
                        float x1 = a.y + tr[base + 1]; if (x1 > bv[c]) { bv[c] = x1; bi[c] = base + 1; }
                        float x2 = a.z + tr[base + 2]; if (x2 > bv[c]) { bv[c] = x2; bi[c] = base + 2; }
                        float x3 = a.w + tr[base + 3]; if (x3 > bv[c]) { bv[c] = x3; bi[c] = base + 3; }
                    }
                }
                float best = bv[0]; int bp = bi[0];
#pragma unroll
                for (int c = 1; c < 4; ++c) { if (bv[c] > best) { best = bv[c]; bp = bi[c]; } }
                bp += h * 64;

                // wave 3: (m, ls) of row t+8 into the ring (slots disjoint from readers)
                if (wave == 3) {
                    float2 v = VR[k];
                    float m = fmaxf(v.x, v.y);
#pragma unroll
                    for (int off = 32; off; off >>= 1) m = fmaxf(m, __shfl_xor(m, off, 64));
                    float s = expf(v.x - m) + expf(v.y - m);
#pragma unroll
                    for (int off = 32; off; off >>= 1) s += __shfl_xor(s, off, 64);
                    if (lane == 0) mls[(t + 8) & 15] = make_float2(m, logf(s));
                }

                // pair combine: even lane (prevs 0..63) vs odd (64..127); strict > keeps lower prev
                float ob  = __shfl_xor(best, 1, 64);
                int   obp = __shfl_xor(bp, 1, 64);
                if (h == 0) {
                    if (ob > best) { best = ob; bp = obp; }
                    float2 ml = mls[t & 15];
                    wa[cur + (cur >> 6) * 4] = best + ((P[k] - ml.x) - ml.y);
                    if (t >= 1) {
                        if (t < TSPLIT) bps[(t - 1) * NN + cur] = (unsigned char)bp;
                        else            wst[(t - TSPLIT) * NN + cur] = (unsigned char)bp;
                    }
                }
                __syncthreads();
            }
        }
        if (wave == 3) {
#pragma unroll
            for (int k = 0; k < 8; ++k) {
                int tt = tb + 16 + k; if (tt > TT - 1) tt = TT - 1;
                VR[k] = ((const float2*)(ub + tt * NN))[lane];
            }
        }
#pragma unroll
        for (int k = 0; k < 8; ++k) P[k] = Nx[k];
    }

    __threadfence();   // tail bp global writes visible to thread 0

    // terminal: argmax(alpha + trans0[EOS][:]), first-max tie-break
    if (tid < NN) {
        float v = alpha[len & 1][tid + (tid >> 6) * 4] + trans[EOS_IDX * NN + tid];
        int idx = tid;
#pragma unroll
        for (int off = 32; off; off >>= 1) {
            float ov = __shfl_xor(v, off, 64);
            int   oi = __shfl_xor(idx, off, 64);
            if (ov > v || (ov == v && oi < idx)) { v = ov; idx = oi; }
        }
        if (lane == 0) { fin_v[wave] = v; fin_i[wave] = idx; }
    }
    __syncthreads();

    for (int t = len + tid; t < TT; t += 256) out[(size_t)b * TT + t] = 0.0f;

    if (tid == 0) {
        float v0 = fin_v[0], v1 = fin_v[1];
        int   i0 = fin_i[0], i1 = fin_i[1];
        float sc; int tag;
        if (v1 > v0) { sc = v1; tag = i1; }
        else         { sc = v0; tag = i0; }
        out[(size_t)BB * TT + b] = sc;

        for (int t = len - 1; t >= 0; --t) {
            out[(size_t)b * TT + t] = (float)tag;
            if (t >= 1) {
                int nb;
                if (t < TSPLIT) nb = bps[(t - 1) * NN + tag];
                else            nb = ((volatile const unsigned char*)wst)[(t - TSPLIT) * NN + tag];
                tag = nb;
            }
        }
    }
}

extern "C" void kernel_launch(void* const* d_in, const int* in_sizes, int n_in,
                              void* d_out, int out_size, void* d_ws, size_t ws_size,
                              hipStream_t stream) {
    const float* unaries = (const float*)d_in[0];
    const float* trans   = (const float*)d_in[1];
    const int*   lengths = (const int*)d_in[2];
    float* out = (float*)d_out;
    unsigned char* ws = (unsigned char*)d_ws;

    hipLaunchKernelGGL(viterbi_kernel, dim3(BB), dim3(256), 0, stream,
                       unaries, trans, lengths, out, ws);
}

// Round 4
// 568.201 us; speedup vs baseline: 1.5050x; 1.5050x over previous
//
#include <hip/hip_runtime.h>

#define BB 256
#define TT 512
#define NN 128
#define GO_IDX 1
#define EOS_IDX 2
#define TSPLIT 496            // bp rows t in [1,TSPLIT) in LDS; [TSPLIT,512) in d_ws (proven 524KB)
#define NEGV (-10000.0f)
// padded alpha slot: x + (x>>5)*4  -> quarter bases at 0,36,72,108 (banks 0,4,8,12; 16B aligned)
#define ASLOT(x) ((x) + (((x) >> 5) << 2))

// ---------- pre-pass: in-place row-wise log_softmax, grid-stride ----------
// per-row math bit-identical to the R2 lsm kernel (same lane mapping + reduction order)
__global__ __launch_bounds__(256) void lsm_kernel(float* __restrict__ u) {
    const int wave = threadIdx.x >> 6, lane = threadIdx.x & 63;
    const int gw = blockIdx.x * 4 + wave;        // 0..8191
    const int NW = 2048 * 4;                     // total waves
    const int R  = BB * TT;                      // 131072 rows
    float2* base = (float2*)u;
    int row = gw;
    float2 v = base[(size_t)row * 64 + lane];
    while (row < R) {
        const int nrow = row + NW;
        float2 vn = make_float2(0.f, 0.f);
        if (nrow < R) vn = base[(size_t)nrow * 64 + lane];   // prefetch next row
        float m = fmaxf(v.x, v.y);
#pragma unroll
        for (int off = 32; off; off >>= 1) m = fmaxf(m, __shfl_xor(m, off, 64));
        float s = expf(v.x - m) + expf(v.y - m);
#pragma unroll
        for (int off = 32; off; off >>= 1) s += __shfl_xor(s, off, 64);
        float ls = logf(s);
        base[(size_t)row * 64 + lane] = make_float2((v.x - m) - ls, (v.y - m) - ls);
        v = vn; row = nrow;
    }
}

// ---------- serial Viterbi: 512 threads, 4 threads per cur (2 waves/SIMD) ----------
__global__ __launch_bounds__(512) void viterbi_kernel(
    const float* __restrict__ probs,     // [B,T,N] already log-softmaxed
    const float* __restrict__ trans,     // [1,N,N] trans0[cur][prev]
    const int*   __restrict__ lengths_raw,
    float* __restrict__ out,             // [B*T] preds then [B] scores
    unsigned char* __restrict__ ws)
{
    __shared__ unsigned char bps[(TSPLIT - 1) * NN];   // 63360 B
    __shared__ __align__(16) float alpha[2][144];      // padded, double-buffered
    __shared__ float fin_v[2];
    __shared__ int   fin_i[2];

    const int tid  = threadIdx.x;
    const int b    = blockIdx.x;
    const int wave = tid >> 6;
    const int lane = tid & 63;
    const int q    = tid & 3;              // prev-quarter owned by this lane
    const int cur  = tid >> 2;             // tag owned by this quad (0..127)

    int len;
    {
        int probe = lengths_raw[1];        // ==0 iff int64 (lengths >= 256 > 0)
        len = (probe == 0) ? lengths_raw[2 * b] : lengths_raw[b];
    }

    // trans chunk in registers: trans0[cur][q*32 + j], j in [0,32)
    float tr[32];
    {
        const float4* t4 = (const float4*)(trans + cur * NN + q * 32);
#pragma unroll
        for (int i = 0; i < 8; ++i) {
            float4 v = t4[i];
            tr[4*i+0] = v.x; tr[4*i+1] = v.y; tr[4*i+2] = v.z; tr[4*i+3] = v.w;
        }
    }

    if (tid < NN) alpha[0][ASLOT(tid)] = (tid == GO_IDX) ? 0.0f : NEGV;

    const float* pb = probs + (size_t)b * TT * NN;
    unsigned char* wst = ws + (size_t)b * ((TT - TSPLIT) * NN);

    // 8-deep register window of p[t][cur] (q==0 lanes only)
    float P[8], Nx[8];
    if (q == 0) {
#pragma unroll
        for (int k = 0; k < 8; ++k) P[k] = pb[k * NN + cur];
    }
    __syncthreads();

    const int nG = (len + 7) >> 3;
    for (int g = 0; g < nG; ++g) {
        const int tb = g * 8;
        if (q == 0) {
#pragma unroll
            for (int k = 0; k < 8; ++k) {
                int tt = tb + 8 + k; if (tt > TT - 1) tt = TT - 1;
                Nx[k] = pb[tt * NN + cur];
            }
        }
#pragma unroll
        for (int k = 0; k < 8; ++k) {
            const int t = tb + k;
            if (t < len) {                         // uniform per block
                const float* ra = alpha[t & 1];
                float*       wa = alpha[(t & 1) ^ 1];
                const float4* a4 = (const float4*)(ra + q * 36);  // banks 0/4/8/12 per quarter
                float bv[4]; int bi[4];
#pragma unroll
                for (int c = 0; c < 4; ++c) {      // 4 chains x 8 prevs
                    bv[c] = -INFINITY; bi[c] = 0;
#pragma unroll
                    for (int r = 0; r < 2; ++r) {
                        float4 a = a4[c * 2 + r];
                        const int base = c * 8 + r * 4;
                        float x0 = a.x + tr[base + 0]; if (x0 > bv[c]) { bv[c] = x0; bi[c] = base + 0; }
                        float x1 = a.y + tr[base + 1]; if (x1 > bv[c]) { bv[c] = x1; bi[c] = base + 1; }
                        float x2 = a.z + tr[base + 2]; if (x2 > bv[c]) { bv[c] = x2; bi[c] = base + 2; }
                        float x3 = a.w + tr[base + 3]; if (x3 > bv[c]) { bv[c] = x3; bi[c] = base + 3; }
                    }
                }
                float best = bv[0]; int bp = bi[0];
#pragma unroll
                for (int c = 1; c < 4; ++c) { if (bv[c] > best) { best = bv[c]; bp = bi[c]; } }
                bp += q * 32;                      // absolute prev index

                // quad combine, values only; exactly one winner lane writes bp.
                // first-max tie-break: lower q (= lower prev range) wins ties.
                float v1 = __shfl_xor(best, 1, 64);     // partner in pair
                float m1 = fmaxf(best, v1);             // pair max
                float v2 = __shfl_xor(m1, 2, 64);       // other pair's max
                float M  = fmaxf(m1, v2);               // quad max
                bool iw = ((q & 1) ? (best > v1) : (best >= v1)) &&
                          ((q & 2) ? (m1 > v2)   : (m1 >= v2));
                if (t >= 1 && iw) {
                    if (t < TSPLIT) bps[(t - 1) * NN + cur] = (unsigned char)bp;
                    else            wst[(t - TSPLIT) * NN + cur] = (unsigned char)bp;
                }
                if (q == 0) wa[ASLOT(cur)] = M + P[k];
                __syncthreads();
            }
        }
#pragma unroll
        for (int k = 0; k < 8; ++k) P[k] = Nx[k];
    }

    __threadfence();   // tail bp global writes visible to thread 0

    // terminal: argmax(alpha + trans0[EOS][:]), first-max tie-break
    if (tid < NN) {
        float v = alpha[len & 1][ASLOT(tid)] + trans[EOS_IDX * NN + tid];
        int idx = tid;
#pragma unroll
        for (int off = 32; off; off >>= 1) {
            float ov = __shfl_xor(v, off, 64);
            int   oi = __shfl_xor(idx, off, 64);
            if (ov > v || (ov == v && oi < idx)) { v = ov; idx = oi; }
        }
        if (lane == 0) { fin_v[wave] = v; fin_i[wave] = idx; }
    }
    __syncthreads();

    for (int t = len + tid; t < TT; t += 512) out[(size_t)b * TT + t] = 0.0f;

    if (tid == 0) {
        float v0 = fin_v[0], v1 = fin_v[1];
        int   i0 = fin_i[0], i1 = fin_i[1];
        float sc; int tag;
        if (v1 > v0) { sc = v1; tag = i1; }
        else         { sc = v0; tag = i0; }
        out[(size_t)BB * TT + b] = sc;

        for (int t = len - 1; t >= 0; --t) {
            out[(size_t)b * TT + t] = (float)tag;
            if (t >= 1) {
                int nb;
                if (t < TSPLIT) nb = bps[(t - 1) * NN + tag];
                else            nb = ((volatile const unsigned char*)wst)[(t - TSPLIT) * NN + tag];
                tag = nb;
            }
        }
    }
}

extern "C" void kernel_launch(void* const* d_in, const int* in_sizes, int n_in,
                              void* d_out, int out_size, void* d_ws, size_t ws_size,
                              hipStream_t stream) {
    float*       unaries = (float*)d_in[0];          // transformed in-place to log-softmax
    const float* trans   = (const float*)d_in[1];
    const int*   lengths = (const int*)d_in[2];
    float* out = (float*)d_out;
    unsigned char* ws = (unsigned char*)d_ws;

    hipLaunchKernelGGL(lsm_kernel, dim3(2048), dim3(256), 0, stream, unaries);
    hipLaunchKernelGGL(viterbi_kernel, dim3(BB), dim3(512), 0, stream,
                       unaries, trans, lengths, out, ws);
}